// Round 4
// baseline (1756.897 us; speedup 1.0000x reference)
//
#include <hip/hip_runtime.h>

typedef __attribute__((ext_vector_type(8))) __bf16 bf16x8;
typedef __attribute__((ext_vector_type(4))) float f32x4;

#define BB 2
#define TT 8
#define CC 64
#define HH 160
#define WW 160
#define HWW 25600
#define RR 16
#define C2 128
#define C4 256
#define C8 512
#define NSTEP 7
#define CHW (CC*HWW)
#define EPSV 1e-5f
#define UPITCH 40
#define VPITCH 40

__device__ __forceinline__ f32x4 mfma16(bf16x8 a, bf16x8 b, f32x4 c) {
    return __builtin_amdgcn_mfma_f32_16x16x32_bf16(a, b, c, 0, 0, 0);
}

// ---------------- pool: mean over H,W for frames 0..6 (fp32 planar input) ----------------
__global__ void pool_kernel(const float* __restrict__ feat, float* __restrict__ pool) {
    int idx = blockIdx.x;                 // b*NSTEP*CC + f*CC + c
    int b = idx / (NSTEP * CC);
    int f = (idx / CC) % NSTEP;
    int c = idx % CC;
    const float4* src = (const float4*)(feat + ((size_t)(b * TT + f) * CC + c) * HWW);
    float s = 0.f;
    for (int i = threadIdx.x; i < HWW / 4; i += 256) {
        float4 v = src[i];
        s += v.x + v.y + v.z + v.w;
    }
    __shared__ float sm[256];
    sm[threadIdx.x] = s;
    __syncthreads();
    for (int off = 128; off > 0; off >>= 1) {
        if (threadIdx.x < off) sm[threadIdx.x] += sm[threadIdx.x + off];
        __syncthreads();
    }
    if (threadIdx.x == 0) pool[idx] = sm[0] * (1.0f / HWW);
}

// ---------------- dynamic depthwise weights -> wdT[bf][t][c] (fp32) ----------------
__global__ void wd_kernel(const float* __restrict__ pool, const float* __restrict__ w1,
                          const float* __restrict__ gamma, const float* __restrict__ beta,
                          const float* __restrict__ mean, const float* __restrict__ var,
                          const float* __restrict__ w2, const float* __restrict__ b2,
                          float* __restrict__ wdT) {
    int bf = blockIdx.x;                  // 0..BB*NSTEP-1
    __shared__ float z[RR];
    int tid = threadIdx.x;                // 64 threads
    if (tid < RR) {
        const float* p = pool + bf * CC;
        float s = 0.f;
        for (int c = 0; c < CC; c++) s += p[c] * w1[tid * CC + c];
        s = (s - mean[tid]) * rsqrtf(var[tid] + EPSV) * gamma[tid] + beta[tid];
        z[tid] = s > 0.f ? s : 0.f;
    }
    __syncthreads();
    for (int o = tid; o < CC * 9; o += 64) {
        float s = b2[o];
        #pragma unroll
        for (int r = 0; r < RR; r++) s += z[r] * w2[o * RR + r];
        int c = o / 9, t = o % 9;
        wdT[bf * 576 + t * CC + c] = s;
    }
}

// ---------------- copy init slice (t=7) fp32 planar into output ----------------
__global__ void copy_init_kernel(const float* __restrict__ feat, float* __restrict__ out) {
    int i = blockIdx.x * 256 + threadIdx.x;   // over BB*CHW/4
    int n4 = CHW / 4;
    int b = i / n4;
    int r = i % n4;
    size_t off = ((size_t)(b * TT + (TT - 1)) * CHW) / 4 + r;
    ((float4*)out)[off] = ((const float4*)feat)[off];
}

// ---------------- prep weights: pack to [N][K] bf16 (+ dwT12 fp32 [t][c512], dwb12) ----------------
__global__ void prep_weights(const float* __restrict__ c1w,
                             const float* __restrict__ pi1, const float* __restrict__ pi2,
                             const float* __restrict__ po1, const float* __restrict__ po2,
                             const float* __restrict__ dw1, const float* __restrict__ dw2,
                             const float* __restrict__ dw1b, const float* __restrict__ dw2b,
                             __bf16* __restrict__ Bc1,
                             __bf16* __restrict__ Bpi1, __bf16* __restrict__ Bpi2,
                             __bf16* __restrict__ Bpo1, __bf16* __restrict__ Bpo2,
                             float* __restrict__ dwT12, float* __restrict__ dwb12) {
    int idx = blockIdx.x * 256 + threadIdx.x;
    if (idx < 147456) {   // conv1: Bc1[oc][t*128+ic]
        int oc = idx / 1152, k = idx % 1152;
        int t = k >> 7, ic = k & 127;
        Bc1[idx] = (__bf16)c1w[(oc * 128 + ic) * 9 + t];
        return;
    }
    idx -= 147456;
    if (idx < 16384) { Bpi1[idx] = (__bf16)pi1[idx]; return; }
    idx -= 16384;
    if (idx < 16384) { Bpi2[idx] = (__bf16)pi2[idx]; return; }
    idx -= 16384;
    if (idx < 16384) { Bpo1[idx] = (__bf16)po1[idx]; return; }
    idx -= 16384;
    if (idx < 16384) { Bpo2[idx] = (__bf16)po2[idx]; return; }
    idx -= 16384;
    if (idx < 4608) {   // dwT12[t][c512]
        int t = idx / 512, c = idx % 512;
        dwT12[t * C8 + c] = (c < 256) ? dw1[c * 9 + t] : dw2[(c - 256) * 9 + t];
        return;
    }
    idx -= 4608;
    if (idx < 512) { dwb12[idx] = (idx < 256) ? dw1b[idx] : dw2b[idx - 256]; }
}

// ---------------- feature planar fp32 -> pixel-major bf16 [bf][p][64] ----------------
__global__ void featPM_kernel(const float* __restrict__ feat, __bf16* __restrict__ featPM) {
    __shared__ float Lt[64 * 68];
    int bf = blockIdx.x / 400;            // b*TT+f, 0..15
    int p0 = (blockIdx.x % 400) * 64;
    int tid = threadIdx.x;
    int c = tid & 63, half = tid >> 6;
    const float* src = feat + ((size_t)bf * CC + c) * HWW + p0 + half * 16;
    #pragma unroll
    for (int k = 0; k < 16; k++) Lt[(half * 16 + k) * 68 + c] = src[k];
    __syncthreads();
    int cg = tid & 7;
    #pragma unroll
    for (int pass = 0; pass < 2; pass++) {
        int pl = (tid >> 3) + pass * 32;
        bf16x8 o;
        #pragma unroll
        for (int j = 0; j < 8; j++) o[j] = (__bf16)Lt[pl * 68 + cg * 8 + j];
        *(bf16x8*)(featPM + ((size_t)bf * HWW + p0 + pl) * CC + cg * 8) = o;
    }
}

// ---------------- dynamic depthwise conv: src (bf16 PM) -> fpPM (bf16 PM) ----------------
__global__ void dyndw_kernel(const __bf16* __restrict__ src, size_t bstr,
                             const float* __restrict__ wdT, const float* __restrict__ kc_bias,
                             __bf16* __restrict__ fpPM, int fx) {
    int gi = blockIdx.x * 256 + threadIdx.x;   // BB*HWW*8
    int c0 = (gi & 7) * 8;
    int rem = gi >> 3;
    int p = rem % HWW;
    int bb = rem / HWW;
    int py = p / WW, px = p % WW;
    float acc[8];
    float4 k0 = *(const float4*)(kc_bias + c0);
    float4 k1 = *(const float4*)(kc_bias + c0 + 4);
    acc[0]=k0.x; acc[1]=k0.y; acc[2]=k0.z; acc[3]=k0.w;
    acc[4]=k1.x; acc[5]=k1.y; acc[6]=k1.z; acc[7]=k1.w;
    const float* wb = wdT + (size_t)(bb * NSTEP + fx) * 576;
    const __bf16* sb = src + (size_t)bb * bstr;
    const int dyA[9] = {-1,-1,-1,0,0,0,1,1,1};
    const int dxA[9] = {-1,0,1,-1,0,1,-1,0,1};
    #pragma unroll
    for (int t = 0; t < 9; t++) {
        int dy = dyA[t], dx = dxA[t];
        if ((unsigned)(py + dy) < HH && (unsigned)(px + dx) < WW) {
            bf16x8 uv = *(const bf16x8*)(sb + (size_t)(p + dy * WW + dx) * CC + c0);
            float4 w0 = *(const float4*)(wb + t * CC + c0);
            float4 w1 = *(const float4*)(wb + t * CC + c0 + 4);
            acc[0] += (float)uv[0] * w0.x; acc[1] += (float)uv[1] * w0.y;
            acc[2] += (float)uv[2] * w0.z; acc[3] += (float)uv[3] * w0.w;
            acc[4] += (float)uv[4] * w1.x; acc[5] += (float)uv[5] * w1.y;
            acc[6] += (float)uv[6] * w1.z; acc[7] += (float)uv[7] * w1.w;
        }
    }
    bf16x8 o;
    #pragma unroll
    for (int j = 0; j < 8; j++) o[j] = (__bf16)acc[j];
    *(bf16x8*)(fpPM + ((size_t)bb * HWW + p) * CC + c0) = o;
}

// ---------------- conv1 implicit-GEMM: M=128px tile, N=128, K=1152 (tap-major) ----------------
__global__ void conv1_gemm(const __bf16* __restrict__ featPM, const __bf16* __restrict__ fpPM,
                           const __bf16* __restrict__ Bc1, const float* __restrict__ bias,
                           __bf16* __restrict__ fusionPM, int fx) {
    __shared__ __align__(16) __bf16 As[128 * 40];
    __shared__ __align__(16) __bf16 Bs[128 * 40];
    const int tid = threadIdx.x;
    const int bb = blockIdx.x / 200;
    const int p0 = (blockIdx.x % 200) * 128;
    const int i = tid >> 1, h = tid & 1;
    const int p = p0 + i;
    const int py = p / WW, px = p % WW;
    const __bf16* featB = featPM + (size_t)(bb * TT + fx) * HWW * CC;
    const __bf16* fpB   = fpPM + (size_t)bb * HWW * CC;
    const int wv = tid >> 6, lane = tid & 63, lm = lane & 15, lq = lane >> 4;
    f32x4 acc[2][8];
    #pragma unroll
    for (int mt = 0; mt < 2; mt++)
        #pragma unroll
        for (int nt = 0; nt < 8; nt++) acc[mt][nt] = (f32x4){0.f, 0.f, 0.f, 0.f};

    for (int ks = 0; ks < 36; ks++) {
        const int t = ks >> 2, ci0 = (ks & 3) * 32;
        const int dy = t / 3 - 1, dx = t % 3 - 1;
        const bool valid = ((unsigned)(py + dy) < HH) && ((unsigned)(px + dx) < WW);
        uint4 a0 = {0,0,0,0}, a1 = {0,0,0,0};
        if (valid) {
            const __bf16* sp = (ci0 < 64)
                ? featB + (size_t)(p + dy * WW + dx) * CC + ci0
                : fpB   + (size_t)(p + dy * WW + dx) * CC + (ci0 - 64);
            a0 = *(const uint4*)(sp + h * 16);
            a1 = *(const uint4*)(sp + h * 16 + 8);
        }
        const __bf16* bp = Bc1 + (size_t)i * 1152 + ks * 32 + h * 16;
        uint4 w0q = *(const uint4*)(bp);
        uint4 w1q = *(const uint4*)(bp + 8);
        __syncthreads();
        *(uint4*)&As[i * 40 + h * 16]     = a0;
        *(uint4*)&As[i * 40 + h * 16 + 8] = a1;
        *(uint4*)&Bs[i * 40 + h * 16]     = w0q;
        *(uint4*)&Bs[i * 40 + h * 16 + 8] = w1q;
        __syncthreads();
        bf16x8 af0 = *(const bf16x8*)&As[((wv * 2 + 0) * 16 + lm) * 40 + lq * 8];
        bf16x8 af1 = *(const bf16x8*)&As[((wv * 2 + 1) * 16 + lm) * 40 + lq * 8];
        #pragma unroll
        for (int nt = 0; nt < 8; nt++) {
            bf16x8 bf = *(const bf16x8*)&Bs[(nt * 16 + lm) * 40 + lq * 8];
            acc[0][nt] = mfma16(af0, bf, acc[0][nt]);
            acc[1][nt] = mfma16(af1, bf, acc[1][nt]);
        }
    }
    __bf16* ob = fusionPM + (size_t)bb * HWW * C2;
    #pragma unroll
    for (int mt = 0; mt < 2; mt++) {
        #pragma unroll
        for (int nt = 0; nt < 8; nt++) {
            const int oc = nt * 16 + lm;
            const float bs = bias[oc];
            #pragma unroll
            for (int r = 0; r < 4; r++) {
                const int pp = p0 + (wv * 2 + mt) * 16 + lq * 4 + r;
                float v = acc[mt][nt][r] + bs;
                v = v > 0.f ? v : 0.1f * v;
                ob[(size_t)pp * C2 + oc] = (__bf16)v;
            }
        }
    }
}

// ---------------- gate_fused: pw1 -> dw3x3 -> pw2 -> gate, one 16x16 tile per block ----------------
// 512 threads (8 waves). Per 32-ch chunk (16 chunks over 512 fused channels):
//   u-GEMM: A direct from global fusionPM (halo 18x18=324 px, padded to 336=21 mt), K=64, N=32 -> Us (LDS)
//   dw3x3:  central 256 px from Us -> Vs (LDS), VALU
//   v-GEMM: partial-K accumulate into persistent acc2[br][mt2][nt]
// Pipelined: dw(c) / barrier / { vgemm(c), ugemm(c+1) } / barrier  (2 barriers per chunk)
__global__ __launch_bounds__(512, 1)
void gate_fused(const __bf16* __restrict__ fusionPM,
                const __bf16* __restrict__ Bpi1, const __bf16* __restrict__ Bpi2,
                const float* __restrict__ pi1b, const float* __restrict__ pi2b,
                const __bf16* __restrict__ Bpo1, const __bf16* __restrict__ Bpo2,
                const float* __restrict__ pob1, const float* __restrict__ pob2,
                const float* __restrict__ dwT12, const float* __restrict__ dwb12,
                float* __restrict__ out, __bf16* __restrict__ outPM, int fx) {
    __shared__ __align__(16) __bf16 Us[336 * UPITCH];   // 26.9 KB
    __shared__ __align__(16) __bf16 Vs[256 * VPITCH];   // 20.5 KB
    const int tid = threadIdx.x;
    const int bb = blockIdx.x / 100;
    const int tile = blockIdx.x % 100;
    const int py0 = (tile / 10) * 16, px0 = (tile % 10) * 16;
    const int wv = tid >> 6, lane = tid & 63, lm = lane & 15, lq = lane >> 4;
    const __bf16* fB = fusionPM + (size_t)bb * HWW * C2;

    f32x4 acc2[2][2][4];   // [br][mt2][nt], persistent pw2 accumulators
    #pragma unroll
    for (int b2 = 0; b2 < 2; b2++)
        #pragma unroll
        for (int m2 = 0; m2 < 2; m2++)
            #pragma unroll
            for (int nt = 0; nt < 4; nt++) acc2[b2][m2][nt] = (f32x4){0.f, 0.f, 0.f, 0.f};

    auto ugemm = [&](int c) {
        const int br = c >> 3, s = c & 7;
        const __bf16* Bpi = br ? Bpi2 : Bpi1;
        const float* pib = br ? pi2b : pi1b;
        bf16x8 bfr[2][2];
        #pragma unroll
        for (int nt = 0; nt < 2; nt++)
            #pragma unroll
            for (int ks = 0; ks < 2; ks++)
                bfr[nt][ks] = *(const bf16x8*)(Bpi + (size_t)(s * 32 + nt * 16 + lm) * 64 + ks * 32 + lq * 8);
        for (int mt = wv; mt < 21; mt += 8) {
            int j = mt * 16 + lm; if (j > 323) j = 323;      // clamp pad rows (values unused)
            int hy = j / 18, hx = j % 18;
            int gy = py0 - 1 + hy, gx = px0 - 1 + hx;
            gy = gy < 0 ? 0 : (gy > 159 ? 159 : gy);          // clamp edges (masked later in dw)
            gx = gx < 0 ? 0 : (gx > 159 ? 159 : gx);
            const __bf16* ap = fB + (size_t)(gy * WW + gx) * C2 + br * 64 + lq * 8;
            bf16x8 a0 = *(const bf16x8*)ap;
            bf16x8 a1 = *(const bf16x8*)(ap + 32);
            #pragma unroll
            for (int nt = 0; nt < 2; nt++) {
                f32x4 uac = (f32x4){0.f, 0.f, 0.f, 0.f};
                uac = mfma16(a0, bfr[nt][0], uac);
                uac = mfma16(a1, bfr[nt][1], uac);
                const float bs = pib[s * 32 + nt * 16 + lm];
                #pragma unroll
                for (int r = 0; r < 4; r++)
                    Us[(mt * 16 + lq * 4 + r) * UPITCH + nt * 16 + lm] = (__bf16)(uac[r] + bs);
            }
        }
    };

    auto dwph = [&](int c) {
        const int cb = (c >> 3) * 256 + (c & 7) * 32;  // global ch base in 512
        #pragma unroll
        for (int k = 0; k < 2; k++) {
            int idx = k * 512 + tid;                   // 0..1023
            int pxl = idx & 255, grp = idx >> 8;       // grp 0..3 (8 ch each)
            int ly = pxl >> 4, lx = pxl & 15;
            int c0 = grp * 8;
            float a[8];
            float4 b0 = *(const float4*)(dwb12 + cb + c0);
            float4 b1 = *(const float4*)(dwb12 + cb + c0 + 4);
            a[0]=b0.x; a[1]=b0.y; a[2]=b0.z; a[3]=b0.w;
            a[4]=b1.x; a[5]=b1.y; a[6]=b1.z; a[7]=b1.w;
            #pragma unroll
            for (int t = 0; t < 9; t++) {
                int dy = t / 3 - 1, dx = t % 3 - 1;
                int gy = py0 + ly + dy, gx = px0 + lx + dx;
                if ((unsigned)gy < HH && (unsigned)gx < WW) {
                    int h = (ly + 1 + dy) * 18 + (lx + 1 + dx);
                    bf16x8 uv = *(const bf16x8*)&Us[h * UPITCH + c0];
                    float4 w0 = *(const float4*)(dwT12 + t * C8 + cb + c0);
                    float4 w1 = *(const float4*)(dwT12 + t * C8 + cb + c0 + 4);
                    a[0] += (float)uv[0] * w0.x; a[1] += (float)uv[1] * w0.y;
                    a[2] += (float)uv[2] * w0.z; a[3] += (float)uv[3] * w0.w;
                    a[4] += (float)uv[4] * w1.x; a[5] += (float)uv[5] * w1.y;
                    a[6] += (float)uv[6] * w1.z; a[7] += (float)uv[7] * w1.w;
                }
            }
            bf16x8 o;
            #pragma unroll
            for (int j = 0; j < 8; j++) o[j] = (__bf16)a[j];
            *(bf16x8*)&Vs[pxl * VPITCH + c0] = o;
        }
    };

    auto vgemm = [&](int c) {
        const int br = c >> 3, s = c & 7;
        const __bf16* Bpo = br ? Bpo2 : Bpo1;
        bf16x8 bv[4];
        #pragma unroll
        for (int nt = 0; nt < 4; nt++)
            bv[nt] = *(const bf16x8*)(Bpo + (size_t)(nt * 16 + lm) * C4 + s * 32 + lq * 8);
        #pragma unroll
        for (int m2 = 0; m2 < 2; m2++) {
            int mt = wv * 2 + m2;
            bf16x8 av = *(const bf16x8*)&Vs[(mt * 16 + lm) * VPITCH + lq * 8];
            #pragma unroll
            for (int nt = 0; nt < 4; nt++)
                acc2[br][m2][nt] = mfma16(av, bv[nt], acc2[br][m2][nt]);
        }
    };

    ugemm(0);
    __syncthreads();
    for (int c = 0; c < 16; c++) {
        dwph(c);
        __syncthreads();
        vgemm(c);
        if (c < 15) ugemm(c + 1);
        __syncthreads();
    }

    // epilogue: gate and write out (fp32 planar) + outPM (bf16 pixel-major)
    __bf16* opB = outPM + (size_t)bb * HWW * CC;
    float* oB = out + (size_t)(bb * TT + fx) * CHW;
    #pragma unroll
    for (int m2 = 0; m2 < 2; m2++) {
        #pragma unroll
        for (int nt = 0; nt < 4; nt++) {
            const int oc = nt * 16 + lm;
            const float b1 = pob1[oc], b2 = pob2[oc];
            #pragma unroll
            for (int r = 0; r < 4; r++) {
                int pxl = (wv * 2 + m2) * 16 + lq * 4 + r;
                int gy = py0 + (pxl >> 4), gx = px0 + (pxl & 15);
                int gp = gy * WW + gx;
                float g1 = 1.f / (1.f + __expf(-(acc2[0][m2][nt][r] + b1)));
                float g2 = 1.f / (1.f + __expf(-(acc2[1][m2][nt][r] + b2)));
                float f1 = (float)fB[(size_t)gp * C2 + oc];
                float f2 = (float)fB[(size_t)gp * C2 + CC + oc];
                float val = f1 * g1 + f2 * g2;
                oB[(size_t)oc * HWW + gp] = val;
                opB[(size_t)gp * CC + oc] = (__bf16)val;
            }
        }
    }
}

extern "C" void kernel_launch(void* const* d_in, const int* in_sizes, int n_in,
                              void* d_out, int out_size, void* d_ws, size_t ws_size,
                              hipStream_t stream) {
    const float* feat     = (const float*)d_in[0];
    const float* kc_w1    = (const float*)d_in[1];
    const float* kc_g     = (const float*)d_in[2];
    const float* kc_be    = (const float*)d_in[3];
    const float* kc_mu    = (const float*)d_in[4];
    const float* kc_var   = (const float*)d_in[5];
    const float* kc_w2    = (const float*)d_in[6];
    const float* kc_b2    = (const float*)d_in[7];
    const float* kc_bias  = (const float*)d_in[8];
    const float* conv1_w  = (const float*)d_in[9];
    const float* conv1_b  = (const float*)d_in[10];
    const float* pi1_w    = (const float*)d_in[11];
    const float* pi1_b    = (const float*)d_in[12];
    const float* dw1_w    = (const float*)d_in[13];
    const float* dw1_b    = (const float*)d_in[14];
    const float* po1_w    = (const float*)d_in[15];
    const float* po1_b    = (const float*)d_in[16];
    const float* pi2_w    = (const float*)d_in[17];
    const float* pi2_b    = (const float*)d_in[18];
    const float* dw2_w    = (const float*)d_in[19];
    const float* dw2_b    = (const float*)d_in[20];
    const float* po2_w    = (const float*)d_in[21];
    const float* po2_b    = (const float*)d_in[22];
    float* out = (float*)d_out;

    char* W = (char*)d_ws;
    __bf16* featPM   = (__bf16*)W; W += (size_t)BB * TT * HWW * CC * 2;   // 52.4 MB
    __bf16* fpPM     = (__bf16*)W; W += (size_t)BB * HWW * CC * 2;        //  6.6 MB
    __bf16* fusionPM = (__bf16*)W; W += (size_t)BB * HWW * C2 * 2;        // 13.1 MB
    __bf16* outPM    = (__bf16*)W; W += (size_t)BB * HWW * CC * 2;        //  6.6 MB
    __bf16* Bc1      = (__bf16*)W; W += 294912;
    __bf16* Bpi1     = (__bf16*)W; W += 32768;
    __bf16* Bpi2     = (__bf16*)W; W += 32768;
    __bf16* Bpo1     = (__bf16*)W; W += 32768;
    __bf16* Bpo2     = (__bf16*)W; W += 32768;
    float*  dwT12    = (float*)W;  W += 18432;
    float*  dwb12    = (float*)W;  W += 2048;
    float*  poolb    = (float*)W;  W += 4096;
    float*  wdT      = (float*)W;  W += 32256;   // total ~79 MB

    prep_weights<<<852, 256, 0, stream>>>(conv1_w, pi1_w, pi2_w, po1_w, po2_w, dw1_w, dw2_w,
                                          dw1_b, dw2_b,
                                          Bc1, Bpi1, Bpi2, Bpo1, Bpo2, dwT12, dwb12);
    featPM_kernel<<<BB * TT * 400, 256, 0, stream>>>(feat, featPM);
    pool_kernel<<<BB * NSTEP * CC, 256, 0, stream>>>(feat, poolb);
    wd_kernel<<<BB * NSTEP, 64, 0, stream>>>(poolb, kc_w1, kc_g, kc_be, kc_mu, kc_var, kc_w2, kc_b2, wdT);
    copy_init_kernel<<<BB * CHW / 4 / 256, 256, 0, stream>>>(feat, out);

    for (int i = 0; i < NSTEP; i++) {
        int fx = NSTEP - 1 - i;   // 6..0
        const __bf16* src = (fx == NSTEP - 1) ? (featPM + (size_t)(TT - 1) * HWW * CC) : outPM;
        size_t bstr = (fx == NSTEP - 1) ? (size_t)TT * HWW * CC : (size_t)HWW * CC;
        dyndw_kernel<<<BB * HWW * 8 / 256, 256, 0, stream>>>(src, bstr, wdT, kc_bias, fpPM, fx);
        conv1_gemm<<<BB * 200, 256, 0, stream>>>(featPM, fpPM, Bc1, conv1_b, fusionPM, fx);
        gate_fused<<<BB * 100, 512, 0, stream>>>(fusionPM, Bpi1, Bpi2, pi1_b, pi2_b,
                                                 Bpo1, Bpo2, po1_b, po2_b,
                                                 dwT12, dwb12, out, outPM, fx);
    }
}